// Round 8
// baseline (419.698 us; speedup 1.0000x reference)
//
#include <hip/hip_runtime.h>

// y[b,f,c] = sum_hw x[b,c,hw] * k[f,c,hw];  out[b*4096 + f*256 + c]
// B=256, F=16, C=256, HW=1024, fp32.
//
// R8: K held in REGISTERS (16 float4/thread; block covers the full 1024-hw
// row: 256 thr x 4 hw). Main loop has ZERO LDS reads and one wave-wide
// coalesced x load per b. In-wave value-halving shuffle reduction; per-wave
// private LDS slab (barrier-free loop); single final barrier + slab reduce.
// R4 lesson: no waves-per-eu hint. grid=512 -> 2 blocks/CU.

constexpr int Ff = 16;
constexpr int Cc = 256;
constexpr int HW = 1024;
constexpr int CHW = Cc * HW;
constexpr int NB = 128;            // b per block
constexpr int NTHREADS = 256;
constexpr int NW = 4;              // waves per block

__device__ __forceinline__ float dot4(float4 a, float4 b) {
    return a.x * b.x + a.y * b.y + a.z * b.z + a.w * b.w;
}

__global__ __launch_bounds__(NTHREADS)
void sle_kernel(const float* __restrict__ x, const float* __restrict__ k,
                float* __restrict__ out) {
    __shared__ float slab[NW * NB * Ff];      // 32 KiB

    const int t    = threadIdx.x;
    const int lane = t & 63;
    const int w    = t >> 6;
    const int c    = blockIdx.x >> 1;         // 0..255
    const int b0   = (blockIdx.x & 1) * NB;   // 0 or 128
    const int hw0  = 4 * t;                   // this thread's 4 hw positions

    // ---- K[f][hw0..hw0+4) for all f -> 16 named float4 (64 VGPRs) ----
    const float* kb = k + (size_t)c * HW + hw0;
#define KLD(F) const float4 K##F = *(const float4*)(kb + (F) * CHW);
    KLD(0)  KLD(1)  KLD(2)  KLD(3)  KLD(4)  KLD(5)  KLD(6)  KLD(7)
    KLD(8)  KLD(9)  KLD(10) KLD(11) KLD(12) KLD(13) KLD(14) KLD(15)
#undef KLD

    // lane -> f mapping after the bit-reversed halving reduction
    const int fmap = ((lane & 1) << 3) | ((lane & 2) << 1)
                   | ((lane & 4) >> 1) | ((lane & 8) >> 3);
    float* myslab = slab + w * (NB * Ff);
    const bool h1 = lane & 1, h2 = lane & 2, h4 = lane & 4, h8 = lane & 8;

    const float* xp = x + (size_t)b0 * CHW + (size_t)c * HW + hw0;

#pragma unroll 4
    for (int j = 0; j < NB; ++j) {
        const float4 xv = *(const float4*)(xp + (size_t)j * CHW);

        // 16 independent 4-FMA dot chains against register-K
        const float s0  = dot4(xv, K0),  s1  = dot4(xv, K1);
        const float s2  = dot4(xv, K2),  s3  = dot4(xv, K3);
        const float s4  = dot4(xv, K4),  s5  = dot4(xv, K5);
        const float s6  = dot4(xv, K6),  s7  = dot4(xv, K7);
        const float s8  = dot4(xv, K8),  s9  = dot4(xv, K9);
        const float s10 = dot4(xv, K10), s11 = dot4(xv, K11);
        const float s12 = dot4(xv, K12), s13 = dot4(xv, K13);
        const float s14 = dot4(xv, K14), s15 = dot4(xv, K15);

        // value-halving butterfly: 16 vals -> 1 val/lane over the 64 lanes.
        // new[j] = (hi ? v[j+n/2] : v[j]) + shfl_xor(hi ? v[j] : v[j+n/2], m)
#define HALVE(OUT, A, B, H, M) \
        const float OUT = ((H) ? (B) : (A)) + __shfl_xor(((H) ? (A) : (B)), (M));
        HALVE(t0, s0, s8,  h1, 1) HALVE(t1, s1, s9,  h1, 1)
        HALVE(t2, s2, s10, h1, 1) HALVE(t3, s3, s11, h1, 1)
        HALVE(t4, s4, s12, h1, 1) HALVE(t5, s5, s13, h1, 1)
        HALVE(t6, s6, s14, h1, 1) HALVE(t7, s7, s15, h1, 1)
        HALVE(u0, t0, t4, h2, 2) HALVE(u1, t1, t5, h2, 2)
        HALVE(u2, t2, t6, h2, 2) HALVE(u3, t3, t7, h2, 2)
        HALVE(v0, u0, u2, h4, 4) HALVE(v1, u1, u3, h4, 4)
        HALVE(r0, v0, v1, h8, 8)
#undef HALVE
        float r = r0;
        r += __shfl_xor(r, 16);
        r += __shfl_xor(r, 32);

        if (lane < 16) myslab[j * Ff + fmap] = r;   // wave-private slab
    }

    __syncthreads();

    // reduce the 4 wave-slabs; 8 outputs per thread
#pragma unroll
    for (int i = 0; i < (NB * Ff) / NTHREADS; ++i) {   // 8
        const int idx = t + NTHREADS * i;              // 0..2047
        const float s = slab[idx]
                      + slab[idx + 1 * NB * Ff]
                      + slab[idx + 2 * NB * Ff]
                      + slab[idx + 3 * NB * Ff];
        const int jb = idx >> 4;
        const int f  = idx & 15;
        out[(size_t)(b0 + jb) * (Ff * Cc) + f * Cc + c] = s;
    }
}

extern "C" void kernel_launch(void* const* d_in, const int* in_sizes, int n_in,
                              void* d_out, int out_size, void* d_ws, size_t ws_size,
                              hipStream_t stream) {
    const float* x = (const float*)d_in[0];
    const float* k = (const float*)d_in[1];
    float* out = (float*)d_out;
    sle_kernel<<<Cc * 2, NTHREADS, 0, stream>>>(x, k, out);  // 512 blocks
}